// Round 12
// baseline (340.472 us; speedup 1.0000x reference)
//
#include <hip/hip_runtime.h>
#include <hip/hip_bf16.h>

#define T_ 1024

typedef __attribute__((ext_vector_type(8))) short short8;
typedef __attribute__((ext_vector_type(4))) float f32x4;
typedef __bf16 bf16x8 __attribute__((ext_vector_type(8)));
typedef __attribute__((ext_vector_type(4))) unsigned short ushort4v;

__device__ __forceinline__ unsigned short f2bf(float f) {
    unsigned u = __float_as_uint(f);
    u += 0x7fffu + ((u >> 16) & 1u);
    return (unsigned short)(u >> 16);
}
__device__ __forceinline__ float bf2f(unsigned short s) {
    return __uint_as_float(((unsigned)s) << 16);
}
__device__ __forceinline__ unsigned short f2h(float f) {
    _Float16 h = (_Float16)f;
    return __builtin_bit_cast(unsigned short, h);
}
__device__ __forceinline__ float h2f(unsigned short u) {
    return (float)__builtin_bit_cast(_Float16, u);
}

// async global->LDS, 16B per lane; LDS dest wave-uniform base (HW adds lane*16)
__device__ __forceinline__ void gload16(const unsigned short* g, unsigned short* l) {
    __builtin_amdgcn_global_load_lds((const __attribute__((address_space(1))) unsigned int*)g,
                                     (__attribute__((address_space(3))) unsigned int*)l,
                                     16, 0, 0);
}

// ---------------- K0a: convert 4 weight matrices f32 -> bf16 ----------------
__global__ __launch_bounds__(256) void k_convert(
    const float* __restrict__ s0, const float* __restrict__ s1,
    const float* __restrict__ s2, const float* __restrict__ s3,
    unsigned short* __restrict__ d0, unsigned short* __restrict__ d1,
    unsigned short* __restrict__ d2, unsigned short* __restrict__ d3) {
    const float* src; unsigned short* dst;
    switch (blockIdx.y) {
        case 0:  src = s0; dst = d0; break;
        case 1:  src = s1; dst = d1; break;
        case 2:  src = s2; dst = d2; break;
        default: src = s3; dst = d3; break;
    }
    int i = (blockIdx.x * 256 + threadIdx.x) * 4;
    float4 v = *(const float4*)(src + i);
    ushort4v ov = { f2bf(v.x), f2bf(v.y), f2bf(v.z), f2bf(v.w) };
    *(ushort4v*)(dst + i) = ov;
}

// ---------------- K0b: build time-shifted xs (bf16) ----------------
__global__ __launch_bounds__(256) void k_xs(const float* __restrict__ x,
                                            unsigned short* __restrict__ xs) {
    int idx = (blockIdx.x * 256 + threadIdx.x) * 4;
    int c = idx & 1023;
    int m = idx >> 10;
    int t = m & 1023;
    float4 v;
    if (c < 512) {
        if (t == 0) { v.x = v.y = v.z = v.w = 0.f; }
        else        { v = *(const float4*)(x + (size_t)(m - 1) * 1024 + c); }
    } else {
        v = *(const float4*)(x + (size_t)m * 1024 + c);
    }
    ushort4v ov = { f2bf(v.x), f2bf(v.y), f2bf(v.z), f2bf(v.w) };
    *(ushort4v*)(xs + (size_t)m * 1024 + c) = ov;
}

// ---------------- shared GEMM body: 128x128 tile, K=1024 ----------------
// Staged via global_load_lds: linear LDS dest (wave-uniform base + lane*16B),
// source chunk pre-swizzled c2 = scp ^ ((row>>1)&3); frag reads use the same XOR.
__device__ __forceinline__ void gemm_body(const unsigned short* __restrict__ A,
                                          const unsigned short* __restrict__ Bt,
                                          int m0, int n0, int tid, f32x4 acc[4][4],
                                          unsigned short (*As)[32], unsigned short (*Bs)[32]) {
    const int lane = tid & 63, w = tid >> 6;
    const int wr = w >> 1, wc = w & 1;
    const int srow = lane >> 2;        // row within wave's 16-row span
    const int scp  = lane & 3;         // chunk slot in LDS row
#pragma unroll
    for (int i = 0; i < 4; i++)
#pragma unroll
        for (int j = 0; j < 4; j++) acc[i][j] = (f32x4){0.f, 0.f, 0.f, 0.f};

    for (int k0 = 0; k0 < 1024; k0 += 32) {
        __syncthreads();
#pragma unroll
        for (int it = 0; it < 2; it++) {
            int base = it * 64 + w * 16;
            int row = base + srow;
            int c2 = scp ^ ((row >> 1) & 3);
            gload16(A + (size_t)(m0 + row) * 1024 + k0 + c2 * 8, &As[base][0]);
            gload16(Bt + (size_t)(n0 + row) * 1024 + k0 + c2 * 8, &Bs[base][0]);
        }
        __syncthreads();
        bf16x8 af[4], bg[4];
        int c = lane >> 4;
#pragma unroll
        for (int i = 0; i < 4; i++) {
            int row = wr * 64 + i * 16 + (lane & 15);
            af[i] = *(const bf16x8*)&As[row][(c ^ ((row >> 1) & 3)) * 8];
        }
#pragma unroll
        for (int j = 0; j < 4; j++) {
            int row = wc * 64 + j * 16 + (lane & 15);
            bg[j] = *(const bf16x8*)&Bs[row][(c ^ ((row >> 1) & 3)) * 8];
        }
#pragma unroll
        for (int i = 0; i < 4; i++)
#pragma unroll
            for (int j = 0; j < 4; j++)
                acc[i][j] = __builtin_amdgcn_mfma_f32_16x16x32_bf16(af[i], bg[j], acc[i][j], 0, 0, 0);
    }
}

// QKV combined: blockIdx.y selects matrix (y>>3) and n-block (y&7).
// Q,K written [b][h][t][d]; V written TRANSPOSED [b][h][d][t] so k_av's B-fragments
// are contiguous 16B global loads (kills the runtime LDS transpose + its conflicts).
__global__ __launch_bounds__(256) void k_gemm_qkv(
    const unsigned short* __restrict__ A,
    const unsigned short* __restrict__ wq, const unsigned short* __restrict__ wk,
    const unsigned short* __restrict__ wv,
    const float* __restrict__ bq, const float* __restrict__ bk, const float* __restrict__ bv,
    unsigned short* __restrict__ qo, unsigned short* __restrict__ ko,
    unsigned short* __restrict__ vo) {
    __shared__ unsigned short As[128][32];
    __shared__ unsigned short Bs[128][32];
    const int mat = blockIdx.y >> 3;
    const unsigned short* Bt = mat == 0 ? wq : (mat == 1 ? wk : wv);
    const float* bias = mat == 0 ? bq : (mat == 1 ? bk : bv);
    unsigned short* out = mat == 0 ? qo : (mat == 1 ? ko : vo);
    const int m0 = blockIdx.x * 128, n0 = (blockIdx.y & 7) * 128;
    const int tid = threadIdx.x, lane = tid & 63, w = tid >> 6;
    const int wr = w >> 1, wc = w & 1;
    f32x4 acc[4][4];
    gemm_body(A, Bt, m0, n0, tid, acc, As, Bs);
#pragma unroll
    for (int i = 0; i < 4; i++) {
        int mbase = m0 + wr * 64 + i * 16 + ((lane >> 4) << 2);
#pragma unroll
        for (int j = 0; j < 4; j++) {
            int n = n0 + wc * 64 + j * 16 + (lane & 15);
            float bv_ = bias[n];
            int h = n >> 6, d = n & 63;
#pragma unroll
            for (int r = 0; r < 4; r++) {
                int mm = mbase + r;
                int b = mm >> 10, t = mm & 1023;
                size_t idx = (mat == 2)
                    ? (size_t)((b * 16 + h) * 64 + d) * 1024 + t    // vT[b,h,d,t]
                    : (size_t)((b * 16 + h) * 1024 + t) * 64 + d;   // q/k[b,h,t,d]
                out[idx] = f2bf(acc[i][j][r] + bv_);
            }
        }
    }
}

// Output projection: f32 out row-major
__global__ __launch_bounds__(256) void k_gemm_out(
    const unsigned short* __restrict__ A, const unsigned short* __restrict__ Bt,
    const float* __restrict__ bias, float* __restrict__ out) {
    __shared__ unsigned short As[128][32];
    __shared__ unsigned short Bs[128][32];
    const int m0 = blockIdx.x * 128, n0 = blockIdx.y * 128;
    const int tid = threadIdx.x, lane = tid & 63, w = tid >> 6;
    const int wr = w >> 1, wc = w & 1;
    f32x4 acc[4][4];
    gemm_body(A, Bt, m0, n0, tid, acc, As, Bs);
#pragma unroll
    for (int i = 0; i < 4; i++) {
        int mbase = m0 + wr * 64 + i * 16 + ((lane >> 4) << 2);
#pragma unroll
        for (int j = 0; j < 4; j++) {
            int n = n0 + wc * 64 + j * 16 + (lane & 15);
            float bv_ = bias[n];
#pragma unroll
            for (int r = 0; r < 4; r++)
                out[(size_t)(mbase + r) * 1024 + n] = acc[i][j][r] + bv_;
        }
    }
}

// ---------------- K2: causal scores -> E = exp(logit) fp16 + per-row inv ----------------
__global__ __launch_bounds__(256) void k_scores(const unsigned short* __restrict__ qb,
                                                const unsigned short* __restrict__ kb,
                                                unsigned short* __restrict__ Eb,
                                                float* __restrict__ invb) {
    __shared__ unsigned short qs[64][64];
    __shared__ unsigned short ks[64][64];
    const int tid = threadIdx.x, lane = tid & 63, w = tid >> 6;
    const int t0 = (15 - (int)blockIdx.x) * 64;   // longest blocks first
    const int bh = blockIdx.y;
    const unsigned short* qp = qb + (size_t)bh * 65536;
    const unsigned short* kp = kb + (size_t)bh * 65536;

#pragma unroll
    for (int it = 0; it < 2; it++) {
        int ch = it * 256 + tid; int row = ch >> 3, c = ch & 7;
        *(short8*)&qs[row][(c ^ (row & 7)) * 8] = *(const short8*)(qp + (size_t)(t0 + row) * 64 + c * 8);
    }
    __syncthreads();
    const int row_a = w * 16 + (lane & 15);
    bf16x8 a0 = *(const bf16x8*)&qs[row_a][(((lane >> 4)    ) ^ (row_a & 7)) * 8];
    bf16x8 a1 = *(const bf16x8*)&qs[row_a][(((lane >> 4) + 4) ^ (row_a & 7)) * 8];
    const int tr = t0 + w * 16 + ((lane >> 4) << 2);
    float l_[4] = {0.f, 0.f, 0.f, 0.f};
    unsigned short* ep = Eb + (size_t)bh * ((size_t)T_ * T_);

    for (int s0 = 0; s0 <= t0 + 63; s0 += 64) {
        __syncthreads();
#pragma unroll
        for (int it = 0; it < 2; it++) {
            int ch = it * 256 + tid; int row = ch >> 3, c = ch & 7;
            *(short8*)&ks[row][(c ^ (row & 7)) * 8] = *(const short8*)(kp + (size_t)(s0 + row) * 64 + c * 8);
        }
        __syncthreads();
        f32x4 S[4];
#pragma unroll
        for (int sf = 0; sf < 4; sf++) {
            int row = sf * 16 + (lane & 15);
            bf16x8 b0 = *(const bf16x8*)&ks[row][(((lane >> 4)    ) ^ (row & 7)) * 8];
            bf16x8 b1 = *(const bf16x8*)&ks[row][(((lane >> 4) + 4) ^ (row & 7)) * 8];
            f32x4 z = (f32x4){0.f, 0.f, 0.f, 0.f};
            z = __builtin_amdgcn_mfma_f32_16x16x32_bf16(a0, b0, z, 0, 0, 0);
            z = __builtin_amdgcn_mfma_f32_16x16x32_bf16(a1, b1, z, 0, 0, 0);
            S[sf] = z;
        }
#pragma unroll
        for (int sf = 0; sf < 4; sf++) {
            int s = s0 + sf * 16 + (lane & 15);
#pragma unroll
            for (int r = 0; r < 4; r++) {
                float es = (s <= tr + r) ? __expf(S[sf][r] * 0.125f) : 0.f;
                l_[r] += es;
                ep[(size_t)(tr + r) * T_ + s] = f2h(es);
            }
        }
    }
    // reduce partial sums across the 16 lanes holding different s-columns
#pragma unroll
    for (int r = 0; r < 4; r++) {
        float ts = l_[r];
        ts += __shfl_xor(ts, 1);
        ts += __shfl_xor(ts, 2);
        ts += __shfl_xor(ts, 4);
        ts += __shfl_xor(ts, 8);
        l_[r] = ts;
    }
    if ((lane & 15) == 0) {
#pragma unroll
        for (int r = 0; r < 4; r++) invb[(size_t)bh * T_ + tr + r] = 1.f / l_[r];
    }
}

// ---------------- K3: head mix, pure-register f32 FMA, load-all-first ILP, IN-PLACE --------
// grid (4 b, 1024 t), b FASTEST: the 4 b-blocks sharing tw[h][t][*] are dispatch-adjacent
// -> tw's 4x redundant reads become L2/L3 hits instead of HBM refetches.
__global__ __launch_bounds__(256) void k_mix6(unsigned short* __restrict__ Sb,
                                              const float* __restrict__ invb,
                                              const float* __restrict__ tw,
                                              const float* __restrict__ mixw) {
    const int b = blockIdx.x, t = blockIdx.y;
    const int send = t | 63;                    // last s that k_av will read
    const int tid = threadIdx.x;
    __shared__ float mw[256];
    __shared__ float inv_s[16];
    mw[tid] = mixw[tid];
    if (tid < 16) inv_s[tid] = invb[(size_t)(b * 16 + tid) * T_ + t];
    __syncthreads();

    const int s4 = tid * 4;
    if (s4 > send) return;
    unsigned short* plane0 = Sb + (size_t)b * 16 * 1048576;
    const unsigned rowb = (unsigned)t * 1024u + (unsigned)s4;

    // ---- phase 1: issue every load up front (32 in flight) ----
    ushort4v e[16];
    float4 tv[16];
#pragma unroll
    for (int h = 0; h < 16; h++)
        e[h] = *(const ushort4v*)(plane0 + (size_t)h * 1048576 + rowb);
#pragma unroll
    for (int h = 0; h < 16; h++)
        tv[h] = *(const float4*)(tw + (size_t)h * 1048576 + rowb);

    // ---- phase 2: p = E * inv * tw ----
    float p[16][4];
#pragma unroll
    for (int h = 0; h < 16; h++) {
        float iv = inv_s[h];
        p[h][0] = h2f(e[h].x) * iv * tv[h].x;
        p[h][1] = h2f(e[h].y) * iv * tv[h].y;
        p[h][2] = h2f(e[h].z) * iv * tv[h].z;
        p[h][3] = h2f(e[h].w) * iv * tv[h].w;
    }

    // ---- phase 3: 16x16 mix + packed stores ----
#pragma unroll
    for (int o = 0; o < 16; o++) {
        float a0 = 0.f, a1 = 0.f, a2 = 0.f, a3 = 0.f;
#pragma unroll
        for (int h = 0; h < 16; h++) {
            float m = mw[o * 16 + h];
            a0 += m * p[h][0];
            a1 += m * p[h][1];
            a2 += m * p[h][2];
            a3 += m * p[h][3];
        }
        ushort4v pk = { f2bf(a0), f2bf(a1), f2bf(a2), f2bf(a3) };
        *(ushort4v*)(plane0 + (size_t)o * 1048576 + rowb) = pk;
    }
}

// ---------------- K4: y1 = attm @ V via vT, no LDS V-transpose ----------------
// B-fragments load directly from vT[b,h,d,s] global: 16B contiguous, L1/L2-resident
// (128 KB per (b,h), reused by 16 t-blocks x 4 waves). Only attm staged in LDS.
__global__ __launch_bounds__(256) void k_av(const unsigned short* __restrict__ att,
                                            const unsigned short* __restrict__ vt,
                                            unsigned short* __restrict__ y1) {
    __shared__ unsigned short as_[64][64];
    const int tid = threadIdx.x, lane = tid & 63, w = tid >> 6;
    const int t0 = (15 - (int)blockIdx.x) * 64;
    const int bh = blockIdx.y;
    const int b = bh >> 4, h = bh & 15;
    const unsigned short* ap = att + (size_t)bh * 1048576;
    const unsigned short* vp = vt + (size_t)bh * 65536;   // [d][s]
    f32x4 acc[4];
#pragma unroll
    for (int j = 0; j < 4; j++) acc[j] = (f32x4){0.f, 0.f, 0.f, 0.f};
    const int row_a = w * 16 + (lane & 15);
    const int dofs = (lane & 15);          // d within 16-chunk
    const int kofs = (lane >> 4) * 8;      // s-offset within 32-slice

    for (int s0 = 0; s0 <= t0 + 63; s0 += 64) {
        __syncthreads();
#pragma unroll
        for (int it = 0; it < 2; it++) {
            int ch = it * 256 + tid;
            int row = ch >> 3, c = ch & 7;
            *(short8*)&as_[row][(c ^ (row & 7)) * 8] =
                *(const short8*)(ap + (size_t)(t0 + row) * 1024 + s0 + c * 8);
        }
        // V fragments from global while as_ staging is in flight
        bf16x8 bg[2][4];
#pragma unroll
        for (int ks = 0; ks < 2; ks++)
#pragma unroll
            for (int j = 0; j < 4; j++)
                bg[ks][j] = *(const bf16x8*)(vp + (size_t)(j * 16 + dofs) * 1024
                                             + s0 + ks * 32 + kofs);
        __syncthreads();
#pragma unroll
        for (int ks = 0; ks < 2; ks++) {
            bf16x8 af = *(const bf16x8*)&as_[row_a][((((lane >> 4) + 4 * ks)) ^ (row_a & 7)) * 8];
#pragma unroll
            for (int j = 0; j < 4; j++)
                acc[j] = __builtin_amdgcn_mfma_f32_16x16x32_bf16(af, bg[ks][j], acc[j], 0, 0, 0);
        }
    }

    int t = t0 + w * 16 + ((lane >> 4) << 2);
#pragma unroll
    for (int j = 0; j < 4; j++) {
        int d = j * 16 + (lane & 15);
#pragma unroll
        for (int r = 0; r < 4; r++)
            y1[(size_t)(b * 1024 + t + r) * 1024 + h * 64 + d] = f2bf(acc[j][r]);
    }
}

// ---------------- host ----------------
extern "C" void kernel_launch(void* const* d_in, const int* in_sizes, int n_in,
                              void* d_out, int out_size, void* d_ws, size_t ws_size,
                              hipStream_t stream) {
    (void)in_sizes; (void)n_in; (void)out_size; (void)ws_size;
    const float* x    = (const float*)d_in[0];
    const float* Wq   = (const float*)d_in[1];
    const float* bq   = (const float*)d_in[2];
    const float* Wk   = (const float*)d_in[3];
    const float* bk   = (const float*)d_in[4];
    const float* Wv   = (const float*)d_in[5];
    const float* bv   = (const float*)d_in[6];
    const float* tw   = (const float*)d_in[7];
    const float* mixw = (const float*)d_in[8];
    const float* Wp   = (const float*)d_in[9];
    const float* bp   = (const float*)d_in[10];

    char* ws = (char*)d_ws;
    size_t off = 0;
    auto alloc = [&](size_t bytes) -> char* {
        char* p = ws + off;
        off += (bytes + 255) & ~(size_t)255;
        return p;
    };
    unsigned short* xs  = (unsigned short*)alloc((size_t)4096 * 1024 * 2);
    unsigned short* wqb = (unsigned short*)alloc((size_t)1024 * 1024 * 2);
    unsigned short* wkb = (unsigned short*)alloc((size_t)1024 * 1024 * 2);
    unsigned short* wvb = (unsigned short*)alloc((size_t)1024 * 1024 * 2);
    unsigned short* wpb = (unsigned short*)alloc((size_t)1024 * 1024 * 2);
    unsigned short* qb  = (unsigned short*)alloc((size_t)64 * 1024 * 64 * 2);
    unsigned short* kb  = (unsigned short*)alloc((size_t)64 * 1024 * 64 * 2);
    unsigned short* vtb = (unsigned short*)alloc((size_t)64 * 1024 * 64 * 2);  // V transposed [b,h,d,t]
    unsigned short* Sb  = (unsigned short*)alloc((size_t)64 * 1024 * 1024 * 2); // E fp16 -> attm bf16 (in place)
    float*          invb = (float*)alloc((size_t)64 * 1024 * 4);
    unsigned short* y1  = (unsigned short*)alloc((size_t)4096 * 1024 * 2);

    k_convert<<<dim3(1024, 4), 256, 0, stream>>>(Wq, Wk, Wv, Wp, wqb, wkb, wvb, wpb);
    k_xs<<<4096, 256, 0, stream>>>(x, xs);
    k_gemm_qkv<<<dim3(32, 24), 256, 0, stream>>>(xs, wqb, wkb, wvb, bq, bk, bv, qb, kb, vtb);
    k_scores<<<dim3(16, 64), 256, 0, stream>>>(qb, kb, Sb, invb);
    k_mix6<<<dim3(4, 1024), 256, 0, stream>>>(Sb, invb, tw, mixw);
    k_av<<<dim3(16, 64), 256, 0, stream>>>(Sb, vtb, y1);
    k_gemm_out<<<dim3(32, 8), 256, 0, stream>>>(y1, wpb, bp, (float*)d_out);
}

// Round 13
// 307.980 us; speedup vs baseline: 1.1055x; 1.1055x over previous
//
#include <hip/hip_runtime.h>
#include <hip/hip_bf16.h>

#define T_ 1024

typedef __attribute__((ext_vector_type(8))) short short8;
typedef __attribute__((ext_vector_type(4))) float f32x4;
typedef __bf16 bf16x8 __attribute__((ext_vector_type(8)));
typedef __attribute__((ext_vector_type(4))) unsigned short ushort4v;

__device__ __forceinline__ unsigned short f2bf(float f) {
    unsigned u = __float_as_uint(f);
    u += 0x7fffu + ((u >> 16) & 1u);
    return (unsigned short)(u >> 16);
}
__device__ __forceinline__ float bf2f(unsigned short s) {
    return __uint_as_float(((unsigned)s) << 16);
}
__device__ __forceinline__ unsigned short f2h(float f) {
    _Float16 h = (_Float16)f;
    return __builtin_bit_cast(unsigned short, h);
}
__device__ __forceinline__ float h2f(unsigned short u) {
    return (float)__builtin_bit_cast(_Float16, u);
}

// async global->LDS, 16B per lane; LDS dest wave-uniform base (HW adds lane*16)
__device__ __forceinline__ void gload16(const unsigned short* g, unsigned short* l) {
    __builtin_amdgcn_global_load_lds((const __attribute__((address_space(1))) unsigned int*)g,
                                     (__attribute__((address_space(3))) unsigned int*)l,
                                     16, 0, 0);
}

// ---------------- K0a: convert 4 weight matrices f32 -> bf16 ----------------
__global__ __launch_bounds__(256) void k_convert(
    const float* __restrict__ s0, const float* __restrict__ s1,
    const float* __restrict__ s2, const float* __restrict__ s3,
    unsigned short* __restrict__ d0, unsigned short* __restrict__ d1,
    unsigned short* __restrict__ d2, unsigned short* __restrict__ d3) {
    const float* src; unsigned short* dst;
    switch (blockIdx.y) {
        case 0:  src = s0; dst = d0; break;
        case 1:  src = s1; dst = d1; break;
        case 2:  src = s2; dst = d2; break;
        default: src = s3; dst = d3; break;
    }
    int i = (blockIdx.x * 256 + threadIdx.x) * 4;
    float4 v = *(const float4*)(src + i);
    ushort4v ov = { f2bf(v.x), f2bf(v.y), f2bf(v.z), f2bf(v.w) };
    *(ushort4v*)(dst + i) = ov;
}

// ---------------- K0b: build time-shifted xs (bf16) ----------------
__global__ __launch_bounds__(256) void k_xs(const float* __restrict__ x,
                                            unsigned short* __restrict__ xs) {
    int idx = (blockIdx.x * 256 + threadIdx.x) * 4;
    int c = idx & 1023;
    int m = idx >> 10;
    int t = m & 1023;
    float4 v;
    if (c < 512) {
        if (t == 0) { v.x = v.y = v.z = v.w = 0.f; }
        else        { v = *(const float4*)(x + (size_t)(m - 1) * 1024 + c); }
    } else {
        v = *(const float4*)(x + (size_t)m * 1024 + c);
    }
    ushort4v ov = { f2bf(v.x), f2bf(v.y), f2bf(v.z), f2bf(v.w) };
    *(ushort4v*)(xs + (size_t)m * 1024 + c) = ov;
}

// ---------------- shared GEMM body: 128x128 tile, K=1024 ----------------
// Staged via global_load_lds: linear LDS dest (wave-uniform base + lane*16B),
// source chunk pre-swizzled c2 = scp ^ ((row>>1)&3); frag reads use the same XOR.
__device__ __forceinline__ void gemm_body(const unsigned short* __restrict__ A,
                                          const unsigned short* __restrict__ Bt,
                                          int m0, int n0, int tid, f32x4 acc[4][4],
                                          unsigned short (*As)[32], unsigned short (*Bs)[32]) {
    const int lane = tid & 63, w = tid >> 6;
    const int wr = w >> 1, wc = w & 1;
    const int srow = lane >> 2;        // row within wave's 16-row span
    const int scp  = lane & 3;         // chunk slot in LDS row
#pragma unroll
    for (int i = 0; i < 4; i++)
#pragma unroll
        for (int j = 0; j < 4; j++) acc[i][j] = (f32x4){0.f, 0.f, 0.f, 0.f};

    for (int k0 = 0; k0 < 1024; k0 += 32) {
        __syncthreads();
#pragma unroll
        for (int it = 0; it < 2; it++) {
            int base = it * 64 + w * 16;
            int row = base + srow;
            int c2 = scp ^ ((row >> 1) & 3);
            gload16(A + (size_t)(m0 + row) * 1024 + k0 + c2 * 8, &As[base][0]);
            gload16(Bt + (size_t)(n0 + row) * 1024 + k0 + c2 * 8, &Bs[base][0]);
        }
        __syncthreads();
        bf16x8 af[4], bg[4];
        int c = lane >> 4;
#pragma unroll
        for (int i = 0; i < 4; i++) {
            int row = wr * 64 + i * 16 + (lane & 15);
            af[i] = *(const bf16x8*)&As[row][(c ^ ((row >> 1) & 3)) * 8];
        }
#pragma unroll
        for (int j = 0; j < 4; j++) {
            int row = wc * 64 + j * 16 + (lane & 15);
            bg[j] = *(const bf16x8*)&Bs[row][(c ^ ((row >> 1) & 3)) * 8];
        }
#pragma unroll
        for (int i = 0; i < 4; i++)
#pragma unroll
            for (int j = 0; j < 4; j++)
                acc[i][j] = __builtin_amdgcn_mfma_f32_16x16x32_bf16(af[i], bg[j], acc[i][j], 0, 0, 0);
    }
}

// QKV combined: blockIdx.y selects matrix (y>>3) and n-block (y&7).
// Q,K written [b][h][t][d]; V written TRANSPOSED [b][h][d][t] (packed 4-t stores).
__global__ __launch_bounds__(256) void k_gemm_qkv(
    const unsigned short* __restrict__ A,
    const unsigned short* __restrict__ wq, const unsigned short* __restrict__ wk,
    const unsigned short* __restrict__ wv,
    const float* __restrict__ bq, const float* __restrict__ bk, const float* __restrict__ bv,
    unsigned short* __restrict__ qo, unsigned short* __restrict__ ko,
    unsigned short* __restrict__ vo) {
    __shared__ unsigned short As[128][32];
    __shared__ unsigned short Bs[128][32];
    const int mat = blockIdx.y >> 3;
    const unsigned short* Bt = mat == 0 ? wq : (mat == 1 ? wk : wv);
    const float* bias = mat == 0 ? bq : (mat == 1 ? bk : bv);
    unsigned short* out = mat == 0 ? qo : (mat == 1 ? ko : vo);
    const int m0 = blockIdx.x * 128, n0 = (blockIdx.y & 7) * 128;
    const int tid = threadIdx.x, lane = tid & 63, w = tid >> 6;
    const int wr = w >> 1, wc = w & 1;
    f32x4 acc[4][4];
    gemm_body(A, Bt, m0, n0, tid, acc, As, Bs);
#pragma unroll
    for (int i = 0; i < 4; i++) {
        int mbase = m0 + wr * 64 + i * 16 + ((lane >> 4) << 2);
#pragma unroll
        for (int j = 0; j < 4; j++) {
            int n = n0 + wc * 64 + j * 16 + (lane & 15);
            float bv_ = bias[n];
            int h = n >> 6, d = n & 63;
            if (mat == 2) {
                // vT[b,h,d,t]: 4 consecutive t (mbase..+3, same b since mbase%4==0)
                int b = mbase >> 10, t = mbase & 1023;
                ushort4v pk = { f2bf(acc[i][j][0] + bv_), f2bf(acc[i][j][1] + bv_),
                                f2bf(acc[i][j][2] + bv_), f2bf(acc[i][j][3] + bv_) };
                *(ushort4v*)(out + (size_t)((b * 16 + h) * 64 + d) * 1024 + t) = pk;
            } else {
#pragma unroll
                for (int r = 0; r < 4; r++) {
                    int mm = mbase + r;
                    int b = mm >> 10, t = mm & 1023;
                    out[(size_t)((b * 16 + h) * 1024 + t) * 64 + d] = f2bf(acc[i][j][r] + bv_);
                }
            }
        }
    }
}

// Output projection: f32 out row-major
__global__ __launch_bounds__(256) void k_gemm_out(
    const unsigned short* __restrict__ A, const unsigned short* __restrict__ Bt,
    const float* __restrict__ bias, float* __restrict__ out) {
    __shared__ unsigned short As[128][32];
    __shared__ unsigned short Bs[128][32];
    const int m0 = blockIdx.x * 128, n0 = blockIdx.y * 128;
    const int tid = threadIdx.x, lane = tid & 63, w = tid >> 6;
    const int wr = w >> 1, wc = w & 1;
    f32x4 acc[4][4];
    gemm_body(A, Bt, m0, n0, tid, acc, As, Bs);
#pragma unroll
    for (int i = 0; i < 4; i++) {
        int mbase = m0 + wr * 64 + i * 16 + ((lane >> 4) << 2);
#pragma unroll
        for (int j = 0; j < 4; j++) {
            int n = n0 + wc * 64 + j * 16 + (lane & 15);
            float bv_ = bias[n];
#pragma unroll
            for (int r = 0; r < 4; r++)
                out[(size_t)(mbase + r) * 1024 + n] = acc[i][j][r] + bv_;
        }
    }
}

// ---------------- K2: causal scores -> E = exp(logit) fp16 + per-row inv ----------------
__global__ __launch_bounds__(256) void k_scores(const unsigned short* __restrict__ qb,
                                                const unsigned short* __restrict__ kb,
                                                unsigned short* __restrict__ Eb,
                                                float* __restrict__ invb) {
    __shared__ unsigned short qs[64][64];
    __shared__ unsigned short ks[64][64];
    const int tid = threadIdx.x, lane = tid & 63, w = tid >> 6;
    const int t0 = (15 - (int)blockIdx.x) * 64;   // longest blocks first
    const int bh = blockIdx.y;
    const unsigned short* qp = qb + (size_t)bh * 65536;
    const unsigned short* kp = kb + (size_t)bh * 65536;

#pragma unroll
    for (int it = 0; it < 2; it++) {
        int ch = it * 256 + tid; int row = ch >> 3, c = ch & 7;
        *(short8*)&qs[row][(c ^ (row & 7)) * 8] = *(const short8*)(qp + (size_t)(t0 + row) * 64 + c * 8);
    }
    __syncthreads();
    const int row_a = w * 16 + (lane & 15);
    bf16x8 a0 = *(const bf16x8*)&qs[row_a][(((lane >> 4)    ) ^ (row_a & 7)) * 8];
    bf16x8 a1 = *(const bf16x8*)&qs[row_a][(((lane >> 4) + 4) ^ (row_a & 7)) * 8];
    const int tr = t0 + w * 16 + ((lane >> 4) << 2);
    float l_[4] = {0.f, 0.f, 0.f, 0.f};
    unsigned short* ep = Eb + (size_t)bh * ((size_t)T_ * T_);

    for (int s0 = 0; s0 <= t0 + 63; s0 += 64) {
        __syncthreads();
#pragma unroll
        for (int it = 0; it < 2; it++) {
            int ch = it * 256 + tid; int row = ch >> 3, c = ch & 7;
            *(short8*)&ks[row][(c ^ (row & 7)) * 8] = *(const short8*)(kp + (size_t)(s0 + row) * 64 + c * 8);
        }
        __syncthreads();
        f32x4 S[4];
#pragma unroll
        for (int sf = 0; sf < 4; sf++) {
            int row = sf * 16 + (lane & 15);
            bf16x8 b0 = *(const bf16x8*)&ks[row][(((lane >> 4)    ) ^ (row & 7)) * 8];
            bf16x8 b1 = *(const bf16x8*)&ks[row][(((lane >> 4) + 4) ^ (row & 7)) * 8];
            f32x4 z = (f32x4){0.f, 0.f, 0.f, 0.f};
            z = __builtin_amdgcn_mfma_f32_16x16x32_bf16(a0, b0, z, 0, 0, 0);
            z = __builtin_amdgcn_mfma_f32_16x16x32_bf16(a1, b1, z, 0, 0, 0);
            S[sf] = z;
        }
#pragma unroll
        for (int sf = 0; sf < 4; sf++) {
            int s = s0 + sf * 16 + (lane & 15);
#pragma unroll
            for (int r = 0; r < 4; r++) {
                float es = (s <= tr + r) ? __expf(S[sf][r] * 0.125f) : 0.f;
                l_[r] += es;
                ep[(size_t)(tr + r) * T_ + s] = f2h(es);
            }
        }
    }
    // reduce partial sums across the 16 lanes holding different s-columns
#pragma unroll
    for (int r = 0; r < 4; r++) {
        float ts = l_[r];
        ts += __shfl_xor(ts, 1);
        ts += __shfl_xor(ts, 2);
        ts += __shfl_xor(ts, 4);
        ts += __shfl_xor(ts, 8);
        l_[r] = ts;
    }
    if ((lane & 15) == 0) {
#pragma unroll
        for (int r = 0; r < 4; r++) invb[(size_t)bh * T_ + tr + r] = 1.f / l_[r];
    }
}

// ---------------- K3: head mix, pure-register f32 FMA, load-all-first ILP, IN-PLACE --------
// grid (4 b, 1024 t), b FASTEST: the 4 b-blocks sharing tw[h][t][*] are dispatch-adjacent.
__global__ __launch_bounds__(256) void k_mix6(unsigned short* __restrict__ Sb,
                                              const float* __restrict__ invb,
                                              const float* __restrict__ tw,
                                              const float* __restrict__ mixw) {
    const int b = blockIdx.x, t = blockIdx.y;
    const int send = t | 63;                    // last s that k_av will read
    const int tid = threadIdx.x;
    __shared__ float mw[256];
    __shared__ float inv_s[16];
    mw[tid] = mixw[tid];
    if (tid < 16) inv_s[tid] = invb[(size_t)(b * 16 + tid) * T_ + t];
    __syncthreads();

    const int s4 = tid * 4;
    if (s4 > send) return;
    unsigned short* plane0 = Sb + (size_t)b * 16 * 1048576;
    const unsigned rowb = (unsigned)t * 1024u + (unsigned)s4;

    // ---- phase 1: issue every load up front (32 in flight) ----
    ushort4v e[16];
    float4 tv[16];
#pragma unroll
    for (int h = 0; h < 16; h++)
        e[h] = *(const ushort4v*)(plane0 + (size_t)h * 1048576 + rowb);
#pragma unroll
    for (int h = 0; h < 16; h++)
        tv[h] = *(const float4*)(tw + (size_t)h * 1048576 + rowb);

    // ---- phase 2: p = E * inv * tw ----
    float p[16][4];
#pragma unroll
    for (int h = 0; h < 16; h++) {
        float iv = inv_s[h];
        p[h][0] = h2f(e[h].x) * iv * tv[h].x;
        p[h][1] = h2f(e[h].y) * iv * tv[h].y;
        p[h][2] = h2f(e[h].z) * iv * tv[h].z;
        p[h][3] = h2f(e[h].w) * iv * tv[h].w;
    }

    // ---- phase 3: 16x16 mix + packed stores ----
#pragma unroll
    for (int o = 0; o < 16; o++) {
        float a0 = 0.f, a1 = 0.f, a2 = 0.f, a3 = 0.f;
#pragma unroll
        for (int h = 0; h < 16; h++) {
            float m = mw[o * 16 + h];
            a0 += m * p[h][0];
            a1 += m * p[h][1];
            a2 += m * p[h][2];
            a3 += m * p[h][3];
        }
        ushort4v pk = { f2bf(a0), f2bf(a1), f2bf(a2), f2bf(a3) };
        *(ushort4v*)(plane0 + (size_t)o * 1048576 + rowb) = pk;
    }
}

// ---------------- K4: y1 = attm @ V; att AND vT both async-staged to LDS ----------------
// vT tile [64 d][64 s] stages coalesced via gload16 (rows contiguous in s) with the
// k_scores source-swizzle pattern; fragment reads use the same XOR. No runtime transpose
// (r11's 8.9M-conflict scatter) and no per-iteration global V latency (r12's regression).
__global__ __launch_bounds__(256) void k_av(const unsigned short* __restrict__ att,
                                            const unsigned short* __restrict__ vt,
                                            unsigned short* __restrict__ y1) {
    __shared__ unsigned short as_[64][64];
    __shared__ unsigned short vsT[64][64];
    const int tid = threadIdx.x, lane = tid & 63, w = tid >> 6;
    const int t0 = (15 - (int)blockIdx.x) * 64;
    const int bh = blockIdx.y;
    const int b = bh >> 4, h = bh & 15;
    const unsigned short* ap = att + (size_t)bh * 1048576;
    const unsigned short* vp = vt + (size_t)bh * 65536;   // [d][s]
    const int srow = lane >> 3, scp = lane & 7;
    f32x4 acc[4];
#pragma unroll
    for (int j = 0; j < 4; j++) acc[j] = (f32x4){0.f, 0.f, 0.f, 0.f};
    const int row_a = w * 16 + (lane & 15);

    for (int s0 = 0; s0 <= t0 + 63; s0 += 64) {
        __syncthreads();
#pragma unroll
        for (int it = 0; it < 2; it++) {
            int base = it * 32 + w * 8;
            int row = base + srow;
            int c2 = scp ^ (row & 7);
            gload16(ap + (size_t)(t0 + row) * 1024 + s0 + c2 * 8, &as_[base][0]);
            gload16(vp + (size_t)row * 1024 + s0 + c2 * 8, &vsT[base][0]);
        }
        __syncthreads();
#pragma unroll
        for (int ks = 0; ks < 2; ks++) {
            bf16x8 af = *(const bf16x8*)&as_[row_a][((((lane >> 4) + 4 * ks)) ^ (row_a & 7)) * 8];
#pragma unroll
            for (int j = 0; j < 4; j++) {
                int rowv = j * 16 + (lane & 15);
                bf16x8 bg = *(const bf16x8*)&vsT[rowv][((((lane >> 4) + 4 * ks)) ^ (rowv & 7)) * 8];
                acc[j] = __builtin_amdgcn_mfma_f32_16x16x32_bf16(af, bg, acc[j], 0, 0, 0);
            }
        }
    }

    int t = t0 + w * 16 + ((lane >> 4) << 2);
#pragma unroll
    for (int j = 0; j < 4; j++) {
        int d = j * 16 + (lane & 15);
#pragma unroll
        for (int r = 0; r < 4; r++)
            y1[(size_t)(b * 1024 + t + r) * 1024 + h * 64 + d] = f2bf(acc[j][r]);
    }
}

// ---------------- host ----------------
extern "C" void kernel_launch(void* const* d_in, const int* in_sizes, int n_in,
                              void* d_out, int out_size, void* d_ws, size_t ws_size,
                              hipStream_t stream) {
    (void)in_sizes; (void)n_in; (void)out_size; (void)ws_size;
    const float* x    = (const float*)d_in[0];
    const float* Wq   = (const float*)d_in[1];
    const float* bq   = (const float*)d_in[2];
    const float* Wk   = (const float*)d_in[3];
    const float* bk   = (const float*)d_in[4];
    const float* Wv   = (const float*)d_in[5];
    const float* bv   = (const float*)d_in[6];
    const float* tw   = (const float*)d_in[7];
    const float* mixw = (const float*)d_in[8];
    const float* Wp   = (const float*)d_in[9];
    const float* bp   = (const float*)d_in[10];

    char* ws = (char*)d_ws;
    size_t off = 0;
    auto alloc = [&](size_t bytes) -> char* {
        char* p = ws + off;
        off += (bytes + 255) & ~(size_t)255;
        return p;
    };
    unsigned short* xs  = (unsigned short*)alloc((size_t)4096 * 1024 * 2);
    unsigned short* wqb = (unsigned short*)alloc((size_t)1024 * 1024 * 2);
    unsigned short* wkb = (unsigned short*)alloc((size_t)1024 * 1024 * 2);
    unsigned short* wvb = (unsigned short*)alloc((size_t)1024 * 1024 * 2);
    unsigned short* wpb = (unsigned short*)alloc((size_t)1024 * 1024 * 2);
    unsigned short* qb  = (unsigned short*)alloc((size_t)64 * 1024 * 64 * 2);
    unsigned short* kb  = (unsigned short*)alloc((size_t)64 * 1024 * 64 * 2);
    unsigned short* vtb = (unsigned short*)alloc((size_t)64 * 1024 * 64 * 2);  // V transposed [b,h,d,t]
    unsigned short* Sb  = (unsigned short*)alloc((size_t)64 * 1024 * 1024 * 2); // E fp16 -> attm bf16 (in place)
    float*          invb = (float*)alloc((size_t)64 * 1024 * 4);
    unsigned short* y1  = (unsigned short*)alloc((size_t)4096 * 1024 * 2);

    k_convert<<<dim3(1024, 4), 256, 0, stream>>>(Wq, Wk, Wv, Wp, wqb, wkb, wvb, wpb);
    k_xs<<<4096, 256, 0, stream>>>(x, xs);
    k_gemm_qkv<<<dim3(32, 24), 256, 0, stream>>>(xs, wqb, wkb, wvb, bq, bk, bv, qb, kb, vtb);
    k_scores<<<dim3(16, 64), 256, 0, stream>>>(qb, kb, Sb, invb);
    k_mix6<<<dim3(4, 1024), 256, 0, stream>>>(Sb, invb, tw, mixw);
    k_av<<<dim3(16, 64), 256, 0, stream>>>(Sb, vtb, y1);
    k_gemm_out<<<dim3(32, 8), 256, 0, stream>>>(y1, wpb, bp, (float*)d_out);
}

// Round 14
// 299.428 us; speedup vs baseline: 1.1371x; 1.0286x over previous
//
#include <hip/hip_runtime.h>
#include <hip/hip_bf16.h>

#define T_ 1024

typedef __attribute__((ext_vector_type(8))) short short8;
typedef __attribute__((ext_vector_type(4))) float f32x4;
typedef __bf16 bf16x8 __attribute__((ext_vector_type(8)));
typedef __attribute__((ext_vector_type(4))) unsigned short ushort4v;

__device__ __forceinline__ unsigned short f2bf(float f) {
    unsigned u = __float_as_uint(f);
    u += 0x7fffu + ((u >> 16) & 1u);
    return (unsigned short)(u >> 16);
}
__device__ __forceinline__ float bf2f(unsigned short s) {
    return __uint_as_float(((unsigned)s) << 16);
}
__device__ __forceinline__ unsigned short f2h(float f) {
    _Float16 h = (_Float16)f;
    return __builtin_bit_cast(unsigned short, h);
}
__device__ __forceinline__ float h2f(unsigned short u) {
    return (float)__builtin_bit_cast(_Float16, u);
}

// async global->LDS, 16B per lane; LDS dest wave-uniform base (HW adds lane*16)
__device__ __forceinline__ void gload16(const unsigned short* g, unsigned short* l) {
    __builtin_amdgcn_global_load_lds((const __attribute__((address_space(1))) unsigned int*)g,
                                     (__attribute__((address_space(3))) unsigned int*)l,
                                     16, 0, 0);
}

// ---------------- K0a: convert 4 weight matrices f32 -> bf16 ----------------
__global__ __launch_bounds__(256) void k_convert(
    const float* __restrict__ s0, const float* __restrict__ s1,
    const float* __restrict__ s2, const float* __restrict__ s3,
    unsigned short* __restrict__ d0, unsigned short* __restrict__ d1,
    unsigned short* __restrict__ d2, unsigned short* __restrict__ d3) {
    const float* src; unsigned short* dst;
    switch (blockIdx.y) {
        case 0:  src = s0; dst = d0; break;
        case 1:  src = s1; dst = d1; break;
        case 2:  src = s2; dst = d2; break;
        default: src = s3; dst = d3; break;
    }
    int i = (blockIdx.x * 256 + threadIdx.x) * 4;
    float4 v = *(const float4*)(src + i);
    ushort4v ov = { f2bf(v.x), f2bf(v.y), f2bf(v.z), f2bf(v.w) };
    *(ushort4v*)(dst + i) = ov;
}

// ---------------- K0b: build time-shifted xs (bf16) ----------------
__global__ __launch_bounds__(256) void k_xs(const float* __restrict__ x,
                                            unsigned short* __restrict__ xs) {
    int idx = (blockIdx.x * 256 + threadIdx.x) * 4;
    int c = idx & 1023;
    int m = idx >> 10;
    int t = m & 1023;
    float4 v;
    if (c < 512) {
        if (t == 0) { v.x = v.y = v.z = v.w = 0.f; }
        else        { v = *(const float4*)(x + (size_t)(m - 1) * 1024 + c); }
    } else {
        v = *(const float4*)(x + (size_t)m * 1024 + c);
    }
    ushort4v ov = { f2bf(v.x), f2bf(v.y), f2bf(v.z), f2bf(v.w) };
    *(ushort4v*)(xs + (size_t)m * 1024 + c) = ov;
}

// ---------------- shared GEMM body: 128x128 tile, K=1024 ----------------
// Staged via global_load_lds: linear LDS dest (wave-uniform base + lane*16B),
// source chunk pre-swizzled c2 = scp ^ ((row>>1)&3); frag reads use the same XOR.
__device__ __forceinline__ void gemm_body(const unsigned short* __restrict__ A,
                                          const unsigned short* __restrict__ Bt,
                                          int m0, int n0, int tid, f32x4 acc[4][4],
                                          unsigned short (*As)[32], unsigned short (*Bs)[32]) {
    const int lane = tid & 63, w = tid >> 6;
    const int wr = w >> 1, wc = w & 1;
    const int srow = lane >> 2;        // row within wave's 16-row span
    const int scp  = lane & 3;         // chunk slot in LDS row
#pragma unroll
    for (int i = 0; i < 4; i++)
#pragma unroll
        for (int j = 0; j < 4; j++) acc[i][j] = (f32x4){0.f, 0.f, 0.f, 0.f};

    for (int k0 = 0; k0 < 1024; k0 += 32) {
        __syncthreads();
#pragma unroll
        for (int it = 0; it < 2; it++) {
            int base = it * 64 + w * 16;
            int row = base + srow;
            int c2 = scp ^ ((row >> 1) & 3);
            gload16(A + (size_t)(m0 + row) * 1024 + k0 + c2 * 8, &As[base][0]);
            gload16(Bt + (size_t)(n0 + row) * 1024 + k0 + c2 * 8, &Bs[base][0]);
        }
        __syncthreads();
        bf16x8 af[4], bg[4];
        int c = lane >> 4;
#pragma unroll
        for (int i = 0; i < 4; i++) {
            int row = wr * 64 + i * 16 + (lane & 15);
            af[i] = *(const bf16x8*)&As[row][(c ^ ((row >> 1) & 3)) * 8];
        }
#pragma unroll
        for (int j = 0; j < 4; j++) {
            int row = wc * 64 + j * 16 + (lane & 15);
            bg[j] = *(const bf16x8*)&Bs[row][(c ^ ((row >> 1) & 3)) * 8];
        }
#pragma unroll
        for (int i = 0; i < 4; i++)
#pragma unroll
            for (int j = 0; j < 4; j++)
                acc[i][j] = __builtin_amdgcn_mfma_f32_16x16x32_bf16(af[i], bg[j], acc[i][j], 0, 0, 0);
    }
}

// QKV combined: blockIdx.y selects matrix (y>>3) and n-block (y&7).
// Q,K written [b][h][t][d]; V written TRANSPOSED [b][h][d][t] (packed 4-t stores).
__global__ __launch_bounds__(256) void k_gemm_qkv(
    const unsigned short* __restrict__ A,
    const unsigned short* __restrict__ wq, const unsigned short* __restrict__ wk,
    const unsigned short* __restrict__ wv,
    const float* __restrict__ bq, const float* __restrict__ bk, const float* __restrict__ bv,
    unsigned short* __restrict__ qo, unsigned short* __restrict__ ko,
    unsigned short* __restrict__ vo) {
    __shared__ unsigned short As[128][32];
    __shared__ unsigned short Bs[128][32];
    const int mat = blockIdx.y >> 3;
    const unsigned short* Bt = mat == 0 ? wq : (mat == 1 ? wk : wv);
    const float* bias = mat == 0 ? bq : (mat == 1 ? bk : bv);
    unsigned short* out = mat == 0 ? qo : (mat == 1 ? ko : vo);
    const int m0 = blockIdx.x * 128, n0 = (blockIdx.y & 7) * 128;
    const int tid = threadIdx.x, lane = tid & 63, w = tid >> 6;
    const int wr = w >> 1, wc = w & 1;
    f32x4 acc[4][4];
    gemm_body(A, Bt, m0, n0, tid, acc, As, Bs);
#pragma unroll
    for (int i = 0; i < 4; i++) {
        int mbase = m0 + wr * 64 + i * 16 + ((lane >> 4) << 2);
#pragma unroll
        for (int j = 0; j < 4; j++) {
            int n = n0 + wc * 64 + j * 16 + (lane & 15);
            float bv_ = bias[n];
            int h = n >> 6, d = n & 63;
            if (mat == 2) {
                // vT[b,h,d,t]: 4 consecutive t (mbase..+3, same b since mbase%4==0)
                int b = mbase >> 10, t = mbase & 1023;
                ushort4v pk = { f2bf(acc[i][j][0] + bv_), f2bf(acc[i][j][1] + bv_),
                                f2bf(acc[i][j][2] + bv_), f2bf(acc[i][j][3] + bv_) };
                *(ushort4v*)(out + (size_t)((b * 16 + h) * 64 + d) * 1024 + t) = pk;
            } else {
#pragma unroll
                for (int r = 0; r < 4; r++) {
                    int mm = mbase + r;
                    int b = mm >> 10, t = mm & 1023;
                    out[(size_t)((b * 16 + h) * 1024 + t) * 64 + d] = f2bf(acc[i][j][r] + bv_);
                }
            }
        }
    }
}

// Output projection: f32 out row-major
__global__ __launch_bounds__(256) void k_gemm_out(
    const unsigned short* __restrict__ A, const unsigned short* __restrict__ Bt,
    const float* __restrict__ bias, float* __restrict__ out) {
    __shared__ unsigned short As[128][32];
    __shared__ unsigned short Bs[128][32];
    const int m0 = blockIdx.x * 128, n0 = blockIdx.y * 128;
    const int tid = threadIdx.x, lane = tid & 63, w = tid >> 6;
    const int wr = w >> 1, wc = w & 1;
    f32x4 acc[4][4];
    gemm_body(A, Bt, m0, n0, tid, acc, As, Bs);
#pragma unroll
    for (int i = 0; i < 4; i++) {
        int mbase = m0 + wr * 64 + i * 16 + ((lane >> 4) << 2);
#pragma unroll
        for (int j = 0; j < 4; j++) {
            int n = n0 + wc * 64 + j * 16 + (lane & 15);
            float bv_ = bias[n];
#pragma unroll
            for (int r = 0; r < 4; r++)
                out[(size_t)(mbase + r) * 1024 + n] = acc[i][j][r] + bv_;
        }
    }
}

// ---------------- K2: causal scores -> E = exp(logit) fp16 + per-row inv ----------------
__global__ __launch_bounds__(256) void k_scores(const unsigned short* __restrict__ qb,
                                                const unsigned short* __restrict__ kb,
                                                unsigned short* __restrict__ Eb,
                                                float* __restrict__ invb) {
    __shared__ unsigned short qs[64][64];
    __shared__ unsigned short ks[64][64];
    const int tid = threadIdx.x, lane = tid & 63, w = tid >> 6;
    const int t0 = (15 - (int)blockIdx.x) * 64;   // longest blocks first
    const int bh = blockIdx.y;
    const unsigned short* qp = qb + (size_t)bh * 65536;
    const unsigned short* kp = kb + (size_t)bh * 65536;

#pragma unroll
    for (int it = 0; it < 2; it++) {
        int ch = it * 256 + tid; int row = ch >> 3, c = ch & 7;
        *(short8*)&qs[row][(c ^ (row & 7)) * 8] = *(const short8*)(qp + (size_t)(t0 + row) * 64 + c * 8);
    }
    __syncthreads();
    const int row_a = w * 16 + (lane & 15);
    bf16x8 a0 = *(const bf16x8*)&qs[row_a][(((lane >> 4)    ) ^ (row_a & 7)) * 8];
    bf16x8 a1 = *(const bf16x8*)&qs[row_a][(((lane >> 4) + 4) ^ (row_a & 7)) * 8];
    const int tr = t0 + w * 16 + ((lane >> 4) << 2);
    float l_[4] = {0.f, 0.f, 0.f, 0.f};
    unsigned short* ep = Eb + (size_t)bh * ((size_t)T_ * T_);

    for (int s0 = 0; s0 <= t0 + 63; s0 += 64) {
        __syncthreads();
#pragma unroll
        for (int it = 0; it < 2; it++) {
            int ch = it * 256 + tid; int row = ch >> 3, c = ch & 7;
            *(short8*)&ks[row][(c ^ (row & 7)) * 8] = *(const short8*)(kp + (size_t)(s0 + row) * 64 + c * 8);
        }
        __syncthreads();
        f32x4 S[4];
#pragma unroll
        for (int sf = 0; sf < 4; sf++) {
            int row = sf * 16 + (lane & 15);
            bf16x8 b0 = *(const bf16x8*)&ks[row][(((lane >> 4)    ) ^ (row & 7)) * 8];
            bf16x8 b1 = *(const bf16x8*)&ks[row][(((lane >> 4) + 4) ^ (row & 7)) * 8];
            f32x4 z = (f32x4){0.f, 0.f, 0.f, 0.f};
            z = __builtin_amdgcn_mfma_f32_16x16x32_bf16(a0, b0, z, 0, 0, 0);
            z = __builtin_amdgcn_mfma_f32_16x16x32_bf16(a1, b1, z, 0, 0, 0);
            S[sf] = z;
        }
#pragma unroll
        for (int sf = 0; sf < 4; sf++) {
            int s = s0 + sf * 16 + (lane & 15);
#pragma unroll
            for (int r = 0; r < 4; r++) {
                float es = (s <= tr + r) ? __expf(S[sf][r] * 0.125f) : 0.f;
                l_[r] += es;
                ep[(size_t)(tr + r) * T_ + s] = f2h(es);
            }
        }
    }
    // reduce partial sums across the 16 lanes holding different s-columns
#pragma unroll
    for (int r = 0; r < 4; r++) {
        float ts = l_[r];
        ts += __shfl_xor(ts, 1);
        ts += __shfl_xor(ts, 2);
        ts += __shfl_xor(ts, 4);
        ts += __shfl_xor(ts, 8);
        l_[r] = ts;
    }
    if ((lane & 15) == 0) {
#pragma unroll
        for (int r = 0; r < 4; r++) invb[(size_t)bh * T_ + tr + r] = 1.f / l_[r];
    }
}

// ---------------- K3: head mix, pure-register f32 FMA, load-all-first ILP, IN-PLACE --------
// grid (1024 t, 4 b), t FASTEST (r11-proven): consecutive blocks walk consecutive t rows
// of the same planes -> sequential DRAM/L2 streams. (r12's b-fastest swap regressed:
// same-t blocks land on different XCD L2s, so tw reuse never happens; reverted.)
__global__ __launch_bounds__(256) void k_mix6(unsigned short* __restrict__ Sb,
                                              const float* __restrict__ invb,
                                              const float* __restrict__ tw,
                                              const float* __restrict__ mixw) {
    const int t = blockIdx.x, b = blockIdx.y;
    const int send = t | 63;                    // last s that k_av will read
    const int tid = threadIdx.x;
    __shared__ float mw[256];
    __shared__ float inv_s[16];
    mw[tid] = mixw[tid];
    if (tid < 16) inv_s[tid] = invb[(size_t)(b * 16 + tid) * T_ + t];
    __syncthreads();

    const int s4 = tid * 4;
    if (s4 > send) return;
    unsigned short* plane0 = Sb + (size_t)b * 16 * 1048576;
    const unsigned rowb = (unsigned)t * 1024u + (unsigned)s4;

    // ---- phase 1: issue every load up front (32 in flight) ----
    ushort4v e[16];
    float4 tv[16];
#pragma unroll
    for (int h = 0; h < 16; h++)
        e[h] = *(const ushort4v*)(plane0 + (size_t)h * 1048576 + rowb);
#pragma unroll
    for (int h = 0; h < 16; h++)
        tv[h] = *(const float4*)(tw + (size_t)h * 1048576 + rowb);

    // ---- phase 2: p = E * inv * tw ----
    float p[16][4];
#pragma unroll
    for (int h = 0; h < 16; h++) {
        float iv = inv_s[h];
        p[h][0] = h2f(e[h].x) * iv * tv[h].x;
        p[h][1] = h2f(e[h].y) * iv * tv[h].y;
        p[h][2] = h2f(e[h].z) * iv * tv[h].z;
        p[h][3] = h2f(e[h].w) * iv * tv[h].w;
    }

    // ---- phase 3: 16x16 mix + packed stores ----
#pragma unroll
    for (int o = 0; o < 16; o++) {
        float a0 = 0.f, a1 = 0.f, a2 = 0.f, a3 = 0.f;
#pragma unroll
        for (int h = 0; h < 16; h++) {
            float m = mw[o * 16 + h];
            a0 += m * p[h][0];
            a1 += m * p[h][1];
            a2 += m * p[h][2];
            a3 += m * p[h][3];
        }
        ushort4v pk = { f2bf(a0), f2bf(a1), f2bf(a2), f2bf(a3) };
        *(ushort4v*)(plane0 + (size_t)o * 1048576 + rowb) = pk;
    }
}

// ---------------- K4: y1 = attm @ V; att AND vT both async-staged to LDS ----------------
// vT tile [64 d][64 s] stages coalesced via gload16 (rows contiguous in s) with the
// k_scores source-swizzle pattern; fragment reads use the same XOR.
__global__ __launch_bounds__(256) void k_av(const unsigned short* __restrict__ att,
                                            const unsigned short* __restrict__ vt,
                                            unsigned short* __restrict__ y1) {
    __shared__ unsigned short as_[64][64];
    __shared__ unsigned short vsT[64][64];
    const int tid = threadIdx.x, lane = tid & 63, w = tid >> 6;
    const int t0 = (15 - (int)blockIdx.x) * 64;
    const int bh = blockIdx.y;
    const int b = bh >> 4, h = bh & 15;
    const unsigned short* ap = att + (size_t)bh * 1048576;
    const unsigned short* vp = vt + (size_t)bh * 65536;   // [d][s]
    const int srow = lane >> 3, scp = lane & 7;
    f32x4 acc[4];
#pragma unroll
    for (int j = 0; j < 4; j++) acc[j] = (f32x4){0.f, 0.f, 0.f, 0.f};
    const int row_a = w * 16 + (lane & 15);

    for (int s0 = 0; s0 <= t0 + 63; s0 += 64) {
        __syncthreads();
#pragma unroll
        for (int it = 0; it < 2; it++) {
            int base = it * 32 + w * 8;
            int row = base + srow;
            int c2 = scp ^ (row & 7);
            gload16(ap + (size_t)(t0 + row) * 1024 + s0 + c2 * 8, &as_[base][0]);
            gload16(vp + (size_t)row * 1024 + s0 + c2 * 8, &vsT[base][0]);
        }
        __syncthreads();
#pragma unroll
        for (int ks = 0; ks < 2; ks++) {
            bf16x8 af = *(const bf16x8*)&as_[row_a][((((lane >> 4) + 4 * ks)) ^ (row_a & 7)) * 8];
#pragma unroll
            for (int j = 0; j < 4; j++) {
                int rowv = j * 16 + (lane & 15);
                bf16x8 bg = *(const bf16x8*)&vsT[rowv][((((lane >> 4) + 4 * ks)) ^ (rowv & 7)) * 8];
                acc[j] = __builtin_amdgcn_mfma_f32_16x16x32_bf16(af, bg, acc[j], 0, 0, 0);
            }
        }
    }

    int t = t0 + w * 16 + ((lane >> 4) << 2);
#pragma unroll
    for (int j = 0; j < 4; j++) {
        int d = j * 16 + (lane & 15);
#pragma unroll
        for (int r = 0; r < 4; r++)
            y1[(size_t)(b * 1024 + t + r) * 1024 + h * 64 + d] = f2bf(acc[j][r]);
    }
}

// ---------------- host ----------------
extern "C" void kernel_launch(void* const* d_in, const int* in_sizes, int n_in,
                              void* d_out, int out_size, void* d_ws, size_t ws_size,
                              hipStream_t stream) {
    (void)in_sizes; (void)n_in; (void)out_size; (void)ws_size;
    const float* x    = (const float*)d_in[0];
    const float* Wq   = (const float*)d_in[1];
    const float* bq   = (const float*)d_in[2];
    const float* Wk   = (const float*)d_in[3];
    const float* bk   = (const float*)d_in[4];
    const float* Wv   = (const float*)d_in[5];
    const float* bv   = (const float*)d_in[6];
    const float* tw   = (const float*)d_in[7];
    const float* mixw = (const float*)d_in[8];
    const float* Wp   = (const float*)d_in[9];
    const float* bp   = (const float*)d_in[10];

    char* ws = (char*)d_ws;
    size_t off = 0;
    auto alloc = [&](size_t bytes) -> char* {
        char* p = ws + off;
        off += (bytes + 255) & ~(size_t)255;
        return p;
    };
    unsigned short* xs  = (unsigned short*)alloc((size_t)4096 * 1024 * 2);
    unsigned short* wqb = (unsigned short*)alloc((size_t)1024 * 1024 * 2);
    unsigned short* wkb = (unsigned short*)alloc((size_t)1024 * 1024 * 2);
    unsigned short* wvb = (unsigned short*)alloc((size_t)1024 * 1024 * 2);
    unsigned short* wpb = (unsigned short*)alloc((size_t)1024 * 1024 * 2);
    unsigned short* qb  = (unsigned short*)alloc((size_t)64 * 1024 * 64 * 2);
    unsigned short* kb  = (unsigned short*)alloc((size_t)64 * 1024 * 64 * 2);
    unsigned short* vtb = (unsigned short*)alloc((size_t)64 * 1024 * 64 * 2);  // V transposed [b,h,d,t]
    unsigned short* Sb  = (unsigned short*)alloc((size_t)64 * 1024 * 1024 * 2); // E fp16 -> attm bf16 (in place)
    float*          invb = (float*)alloc((size_t)64 * 1024 * 4);
    unsigned short* y1  = (unsigned short*)alloc((size_t)4096 * 1024 * 2);

    k_convert<<<dim3(1024, 4), 256, 0, stream>>>(Wq, Wk, Wv, Wp, wqb, wkb, wvb, wpb);
    k_xs<<<4096, 256, 0, stream>>>(x, xs);
    k_gemm_qkv<<<dim3(32, 24), 256, 0, stream>>>(xs, wqb, wkb, wvb, bq, bk, bv, qb, kb, vtb);
    k_scores<<<dim3(16, 64), 256, 0, stream>>>(qb, kb, Sb, invb);
    k_mix6<<<dim3(1024, 4), 256, 0, stream>>>(Sb, invb, tw, mixw);
    k_av<<<dim3(16, 64), 256, 0, stream>>>(Sb, vtb, y1);
    k_gemm_out<<<dim3(32, 8), 256, 0, stream>>>(y1, wpb, bp, (float*)d_out);
}